// Round 6
// baseline (144.714 us; speedup 1.0000x reference)
//
#include <hip/hip_runtime.h>

typedef __attribute__((ext_vector_type(4))) short short4v;
typedef __attribute__((ext_vector_type(8))) short short8v;
typedef __attribute__((ext_vector_type(4))) float float4v;
typedef __attribute__((ext_vector_type(4))) int int4v;

#define GLD_LDS16(gsrc, ldst)                                                             \
    __builtin_amdgcn_global_load_lds(                                                     \
        (const __attribute__((address_space(1))) void*)(gsrc),                            \
        (__attribute__((address_space(3))) void*)(ldst), 16, 0, 0)

__device__ __forceinline__ short f2bf(float f) {
    unsigned u = __builtin_bit_cast(unsigned, f);
    u += 0x7fffu + ((u >> 16) & 1u);
    return (short)(u >> 16);
}

// ---------------- x: fp32 -> bf16 (vectorized) ----------------
__global__ void k_cvt_x(const float* __restrict__ x, short* __restrict__ xb) {
    int i = blockIdx.x * blockDim.x + threadIdx.x;
    float4v v = ((const float4v*)x)[i];
    short4v o;
    o[0] = f2bf(v[0]); o[1] = f2bf(v[1]); o[2] = f2bf(v[2]); o[3] = f2bf(v[3]);
    ((short4v*)xb)[i] = o;
}

// ---------------- W[k][n] fp32 -> Wt[n][k] bf16 (LDS tile transpose) ----------------
__global__ void k_transpose(const float* __restrict__ W0, const float* __restrict__ W1,
                            const float* __restrict__ W2, const float* __restrict__ W3,
                            short* __restrict__ Wt) {
    const float* W = blockIdx.z == 0 ? W0 : blockIdx.z == 1 ? W1 : blockIdx.z == 2 ? W2 : W3;
    short* dst = Wt + (size_t)blockIdx.z * 1024 * 1024;
    __shared__ float tile[32][33];
    int x0 = blockIdx.x * 32, y0 = blockIdx.y * 32;
    int tx = threadIdx.x, ty = threadIdx.y;
#pragma unroll
    for (int j = 0; j < 4; j++) {
        int r = ty + j * 8;
        tile[r][tx] = W[(size_t)(y0 + r) * 1024 + x0 + tx];
    }
    __syncthreads();
#pragma unroll
    for (int j = 0; j < 4; j++) {
        int r = ty + j * 8;
        dst[(size_t)(x0 + r) * 1024 + y0 + tx] = f2bf(tile[tx][r]);
    }
}

// ---------------- bf16 MFMA GEMM v2: 128x128 tile, BK=64, 8 waves, 2-phase dbuf ------
template <int MODE>
__launch_bounds__(512, 4)
__global__ void k_gemm2(const short* __restrict__ A, const short* __restrict__ Bt,
                        short* __restrict__ out0, short* __restrict__ out1,
                        float* __restrict__ outF) {
    __shared__ short As[2][128][64];
    __shared__ short Bs[2][128][64];
    int t = threadIdx.x;
    int l = t & 63, w = t >> 6;
    int wm = w >> 2, wn = w & 3;
    int lr = l & 15, lg = l >> 4;
    int m0 = blockIdx.x * 128, n0 = blockIdx.y * 128;
    const short* Bp = Bt + (MODE == 0 ? ((size_t)blockIdx.z << 20) : 0);

    int srow = l >> 3;
    int sg = (l & 7) ^ srow;
    const short* Ab0 = A + (size_t)(m0 + w * 8 + srow) * 1024 + sg * 8;
    const short* Ab1 = Ab0 + 64 * 1024;
    const short* Bb0 = Bp + (size_t)(n0 + w * 8 + srow) * 1024 + sg * 8;
    const short* Bb1 = Bb0 + 64 * 1024;

    float4v acc[4][2] = {};

#define STAGE(bb, k0)                                   \
    do {                                                \
        GLD_LDS16(Ab0 + (k0), &As[bb][w * 8][0]);       \
        GLD_LDS16(Ab1 + (k0), &As[bb][64 + w * 8][0]);  \
        GLD_LDS16(Bb0 + (k0), &Bs[bb][w * 8][0]);       \
        GLD_LDS16(Bb1 + (k0), &Bs[bb][64 + w * 8][0]);  \
    } while (0)

    STAGE(0, 0);
    __syncthreads();
    int cur = 0;

    for (int kt = 0; kt < 16; kt++) {
        if (kt + 1 < 16) STAGE(cur ^ 1, (kt + 1) * 64);
#pragma unroll
        for (int ks = 0; ks < 2; ks++) {
            short8v af[4], bfv[2];
            int hh = ks * 4 + lg;
            int sw = ((hh ^ (lr & 7)) * 8);
#pragma unroll
            for (int fm = 0; fm < 4; fm++)
                af[fm] = *(const short8v*)&As[cur][wm * 64 + fm * 16 + lr][sw];
#pragma unroll
            for (int fn = 0; fn < 2; fn++)
                bfv[fn] = *(const short8v*)&Bs[cur][wn * 32 + fn * 16 + lr][sw];
            __builtin_amdgcn_s_setprio(1);
#pragma unroll
            for (int fm = 0; fm < 4; fm++)
#pragma unroll
                for (int fn = 0; fn < 2; fn++)
                    acc[fm][fn] = (MODE == 1)
                        ? __builtin_amdgcn_mfma_f32_16x16x32_bf16(bfv[fn], af[fm], acc[fm][fn], 0, 0, 0)
                        : __builtin_amdgcn_mfma_f32_16x16x32_bf16(af[fm], bfv[fn], acc[fm][fn], 0, 0, 0);
            __builtin_amdgcn_s_setprio(0);
        }
        __syncthreads();
        cur ^= 1;
    }
#undef STAGE

    if (MODE == 0) {
        short* out = (blockIdx.z == 0) ? out0 : out1;
        float scale = (blockIdx.z == 0) ? 0.125f * 1.44269504088896f : 1.0f;
#pragma unroll
        for (int fm = 0; fm < 4; fm++)
#pragma unroll
            for (int fn = 0; fn < 2; fn++)
#pragma unroll
                for (int r = 0; r < 4; r++) {
                    int m = m0 + wm * 64 + fm * 16 + lg * 4 + r;
                    int n = n0 + wn * 32 + fn * 16 + lr;
                    float v = acc[fm][fn][r] * scale;
                    int b = m >> 11, s = m & 2047, h = n >> 6, dh = n & 63;
                    out[(((size_t)(b * 16 + h)) * 2048 + s) * 64 + dh] = f2bf(v);
                }
    } else if (MODE == 1) {
#pragma unroll
        for (int fm = 0; fm < 4; fm++)
#pragma unroll
            for (int fn = 0; fn < 2; fn++)
#pragma unroll
                for (int r = 0; r < 4; r++) {
                    int n = n0 + wn * 32 + fn * 16 + lg * 4 + r;
                    int m = m0 + wm * 64 + fm * 16 + lr;
                    int b = m >> 11, s = m & 2047, h = n >> 6, dh = n & 63;
                    out0[(((size_t)(b * 16 + h)) * 64 + dh) * 2048 + s] = f2bf(acc[fm][fn][r]);
                }
    } else {
#pragma unroll
        for (int fm = 0; fm < 4; fm++)
#pragma unroll
            for (int fn = 0; fn < 2; fn++)
#pragma unroll
                for (int r = 0; r < 4; r++) {
                    int m = m0 + wm * 64 + fm * 16 + lg * 4 + r;
                    int n = n0 + wn * 32 + fn * 16 + lr;
                    outF[(size_t)m * 1024 + n] = acc[fm][fn][r];
                }
    }
}

// ---------------- causal flash attention v5 ----------------
// K staged in LDS (shared x4 waves, dbuf, swizzled); V read DIRECT from global
// (L1-served: all 4 waves use identical V addresses; L2-resident via XCD remap).
// Defer-max: no cross-lane reduce in the common path.
__launch_bounds__(256, 2)
__global__ void k_attn(const short* __restrict__ Qb, const short* __restrict__ Kb,
                       const short* __restrict__ Vtb, short* __restrict__ Ob) {
    __shared__ short K_lds[2][64][64];
    __shared__ short p_lds[4][16][72];
    int t = threadIdx.x;
    int l = t & 63, w = t >> 6;
    int lr = l & 15, lg = l >> 4;

    int L = blockIdx.y * 16 + blockIdx.x;
    int bh = (L & 7) * 4 + ((L >> 3) & 3);
    int p = L >> 5;

    const short* Qp = Qb + (size_t)bh * 2048 * 64;
    const short* Kp = Kb + (size_t)bh * 2048 * 64;
    const short* Vp = Vtb + (size_t)bh * 64 * 2048;

    int n0 = 32 - p;
    int n1 = p + 1;
    const int total = 33;

    auto stageK = [&](int bb, int kv0) {
#pragma unroll
        for (int i = 0; i < 2; i++) {
            int s = w * 64 + i * 256 + l;
            int row = s >> 3, cg = s & 7;
            int cs = (cg ^ (row & 7)) * 8;
            GLD_LDS16(&Kp[(size_t)(kv0 + row) * 64 + cs],
                      (short*)K_lds[bb] + (size_t)(w * 64 + i * 256) * 8);
        }
    };

    stageK(0, 0);

    int tile = 31 - p;
    int q0 = tile * 64 + w * 16;
    short8v qf0 = *(const short8v*)&Qp[(size_t)(q0 + lr) * 64 + lg * 8];
    short8v qf1 = *(const short8v*)&Qp[(size_t)(q0 + lr) * 64 + 32 + lg * 8];

    float4v o[4] = {};
    float mr[4] = {-3e38f, -3e38f, -3e38f, -3e38f};
    float lsum[4] = {0.f, 0.f, 0.f, 0.f};
    int cur = 0;
    int b = bh >> 4, h = bh & 15;

    __syncthreads();

    for (int ci = 0; ci < total; ci++) {
        bool second = ci >= n0;
        int ntile = second ? n1 : n0;
        int c = second ? ci - n0 : ci;
        int kv0 = c * 64;

        int cin = ci + 1;
        if (cin < total) {
            int kvn = (cin < n0) ? cin * 64 : (cin - n0) * 64;
            stageK(cur ^ 1, kvn);
        }

        // V fragments direct from global (identical addrs across waves -> L1 hits);
        // issued early so latency hides under QK^T + softmax.
        short8v vf[8];
#pragma unroll
        for (int dt = 0; dt < 4; dt++) {
            vf[dt]     = *(const short8v*)&Vp[(size_t)(dt * 16 + lr) * 2048 + kv0 + lg * 8];
            vf[4 + dt] = *(const short8v*)&Vp[(size_t)(dt * 16 + lr) * 2048 + kv0 + 32 + lg * 8];
        }

        // ---- QK^T from swizzled LDS ----
        const short* Kf = (const short*)K_lds[cur];
        float4v s[4] = {};
        __builtin_amdgcn_s_setprio(1);
#pragma unroll
        for (int t4 = 0; t4 < 4; t4++) {
            int krow = t4 * 16 + lr;
            int sw = (krow & 7);
            short8v kfa = *(const short8v*)&Kf[krow * 64 + ((lg ^ sw) * 8)];
            short8v kfb = *(const short8v*)&Kf[krow * 64 + (((lg ^ 4) ^ sw) * 8)];
            s[t4] = __builtin_amdgcn_mfma_f32_16x16x32_bf16(qf0, kfa, s[t4], 0, 0, 0);
            s[t4] = __builtin_amdgcn_mfma_f32_16x16x32_bf16(qf1, kfb, s[t4], 0, 0, 0);
        }
        __builtin_amdgcn_s_setprio(0);

        if (c == ntile - 1) {
#pragma unroll
            for (int t4 = 0; t4 < 4; t4++)
#pragma unroll
                for (int r = 0; r < 4; r++) {
                    int row = q0 + lg * 4 + r;
                    if (kv0 + t4 * 16 + lr > row) s[t4][r] = -3e38f;
                }
        }

        // ---- defer-max online softmax: no cross-lane reduce in common path ----
        float mx[4];
#pragma unroll
        for (int r = 0; r < 4; r++)
            mx[r] = fmaxf(fmaxf(s[0][r], s[1][r]), fmaxf(s[2][r], s[3][r]));
        float worst = fmaxf(fmaxf(mx[0] - mr[0], mx[1] - mr[1]),
                            fmaxf(mx[2] - mr[2], mx[3] - mr[3]));
        if (!__all(worst <= 8.f)) {     // rare: first chunk (or big max jump)
#pragma unroll
            for (int r = 0; r < 4; r++) {
                float m_ = mx[r];
                m_ = fmaxf(m_, __shfl_xor(m_, 1));
                m_ = fmaxf(m_, __shfl_xor(m_, 2));
                m_ = fmaxf(m_, __shfl_xor(m_, 4));
                m_ = fmaxf(m_, __shfl_xor(m_, 8));
                float mnew = fmaxf(mr[r], m_);
                float sc = __builtin_amdgcn_exp2f(mr[r] - mnew);
                mr[r] = mnew;
                lsum[r] *= sc;
                o[0][r] *= sc; o[1][r] *= sc; o[2][r] *= sc; o[3][r] *= sc;
            }
        }
#pragma unroll
        for (int r = 0; r < 4; r++) {
            float e0 = __builtin_amdgcn_exp2f(s[0][r] - mr[r]);
            float e1 = __builtin_amdgcn_exp2f(s[1][r] - mr[r]);
            float e2 = __builtin_amdgcn_exp2f(s[2][r] - mr[r]);
            float e3 = __builtin_amdgcn_exp2f(s[3][r] - mr[r]);
            lsum[r] += (e0 + e1) + (e2 + e3);
            p_lds[w][lg * 4 + r][lr]      = f2bf(e0);
            p_lds[w][lg * 4 + r][16 + lr] = f2bf(e1);
            p_lds[w][lg * 4 + r][32 + lr] = f2bf(e2);
            p_lds[w][lg * 4 + r][48 + lr] = f2bf(e3);
        }

        short8v pa0 = *(const short8v*)&p_lds[w][lr][lg * 8];
        short8v pa1 = *(const short8v*)&p_lds[w][lr][32 + lg * 8];

        // ---- PV with direct-loaded V ----
        __builtin_amdgcn_s_setprio(1);
#pragma unroll
        for (int dt = 0; dt < 4; dt++) {
            o[dt] = __builtin_amdgcn_mfma_f32_16x16x32_bf16(pa0, vf[dt], o[dt], 0, 0, 0);
            o[dt] = __builtin_amdgcn_mfma_f32_16x16x32_bf16(pa1, vf[4 + dt], o[dt], 0, 0, 0);
        }
        __builtin_amdgcn_s_setprio(0);

        // ---- tile finalize / switch ----
        if (c == ntile - 1) {
            float inv[4];
#pragma unroll
            for (int r = 0; r < 4; r++) {
                float ls = lsum[r];
                ls += __shfl_xor(ls, 1);
                ls += __shfl_xor(ls, 2);
                ls += __shfl_xor(ls, 4);
                ls += __shfl_xor(ls, 8);
                inv[r] = 1.0f / ls;
            }
#pragma unroll
            for (int dt = 0; dt < 4; dt++)
#pragma unroll
                for (int r = 0; r < 4; r++) {
                    int q = q0 + lg * 4 + r;
                    Ob[((size_t)(b * 2048 + q)) * 1024 + h * 64 + dt * 16 + lr] = f2bf(o[dt][r] * inv[r]);
                }
            if (!second) {
                tile = p;
                q0 = tile * 64 + w * 16;
                qf0 = *(const short8v*)&Qp[(size_t)(q0 + lr) * 64 + lg * 8];
                qf1 = *(const short8v*)&Qp[(size_t)(q0 + lr) * 64 + 32 + lg * 8];
#pragma unroll
                for (int dt = 0; dt < 4; dt++) o[dt] = float4v{0.f, 0.f, 0.f, 0.f};
#pragma unroll
                for (int r = 0; r < 4; r++) { mr[r] = -3e38f; lsum[r] = 0.f; }
            }
        }

        __syncthreads();   // K buffer flip: reads of cur done, stage of cur^1 drained
        cur ^= 1;
    }
}

extern "C" void kernel_launch(void* const* d_in, const int* in_sizes, int n_in,
                              void* d_out, int out_size, void* d_ws, size_t ws_size,
                              hipStream_t stream) {
    const float* x  = (const float*)d_in[0];
    const float* Wq = (const float*)d_in[1];
    const float* Wk = (const float*)d_in[2];
    const float* Wv = (const float*)d_in[3];
    const float* Wo = (const float*)d_in[4];
    float* out = (float*)d_out;

    char* ws = (char*)d_ws;
    short* xb  = (short*)(ws);                 // [4096][1024] bf16       8 MB
    short* Wtb = (short*)(ws + 8388608);       // 4 x [1024 n][1024 k]    8 MB
    short* Qb  = (short*)(ws + 16777216);      // [B,H,S,Dh] (pre-scaled) 8 MB
    short* Kb  = (short*)(ws + 25165824);      // [B,H,S,Dh]              8 MB
    short* Vtb = (short*)(ws + 33554432);      // [B,H,Dh,S]              8 MB
    short* Ob  = (short*)(ws + 41943040);      // [B,S,D] bf16            8 MB

    k_cvt_x<<<4096, 256, 0, stream>>>(x, xb);
    k_transpose<<<dim3(32, 32, 4), dim3(32, 8), 0, stream>>>(Wq, Wk, Wv, Wo, Wtb);
    k_gemm2<0><<<dim3(32, 8, 2), 512, 0, stream>>>(xb, Wtb, Qb, Kb, nullptr);
    k_gemm2<1><<<dim3(32, 8), 512, 0, stream>>>(xb, Wtb + 2 * 1048576, Vtb, nullptr, nullptr);
    k_attn<<<dim3(16, 32), 256, 0, stream>>>(Qb, Kb, Vtb, Ob);
    k_gemm2<2><<<dim3(32, 8), 512, 0, stream>>>(Ob, Wtb + 3 * 1048576, nullptr, nullptr, out);
}

// Round 7
// 135.455 us; speedup vs baseline: 1.0684x; 1.0684x over previous
//
#include <hip/hip_runtime.h>

typedef __attribute__((ext_vector_type(4))) short short4v;
typedef __attribute__((ext_vector_type(8))) short short8v;
typedef __attribute__((ext_vector_type(4))) float float4v;
typedef __attribute__((ext_vector_type(4))) int int4v;

#define GLD_LDS16(gsrc, ldst)                                                             \
    __builtin_amdgcn_global_load_lds(                                                     \
        (const __attribute__((address_space(1))) void*)(gsrc),                            \
        (__attribute__((address_space(3))) void*)(ldst), 16, 0, 0)

__device__ __forceinline__ short f2bf(float f) {
    unsigned u = __builtin_bit_cast(unsigned, f);
    u += 0x7fffu + ((u >> 16) & 1u);
    return (short)(u >> 16);
}

// ---------------- x: fp32 -> bf16 (vectorized) ----------------
__global__ void k_cvt_x(const float* __restrict__ x, short* __restrict__ xb) {
    int i = blockIdx.x * blockDim.x + threadIdx.x;
    float4v v = ((const float4v*)x)[i];
    short4v o;
    o[0] = f2bf(v[0]); o[1] = f2bf(v[1]); o[2] = f2bf(v[2]); o[3] = f2bf(v[3]);
    ((short4v*)xb)[i] = o;
}

// ---------------- W[k][n] fp32 -> Wt[n][k] bf16 (LDS tile transpose) ----------------
__global__ void k_transpose(const float* __restrict__ W0, const float* __restrict__ W1,
                            const float* __restrict__ W2, const float* __restrict__ W3,
                            short* __restrict__ Wt) {
    const float* W = blockIdx.z == 0 ? W0 : blockIdx.z == 1 ? W1 : blockIdx.z == 2 ? W2 : W3;
    short* dst = Wt + (size_t)blockIdx.z * 1024 * 1024;
    __shared__ float tile[32][33];
    int x0 = blockIdx.x * 32, y0 = blockIdx.y * 32;
    int tx = threadIdx.x, ty = threadIdx.y;
#pragma unroll
    for (int j = 0; j < 4; j++) {
        int r = ty + j * 8;
        tile[r][tx] = W[(size_t)(y0 + r) * 1024 + x0 + tx];
    }
    __syncthreads();
#pragma unroll
    for (int j = 0; j < 4; j++) {
        int r = ty + j * 8;
        dst[(size_t)(x0 + r) * 1024 + y0 + tx] = f2bf(tile[tx][r]);
    }
}

// ---------------- bf16 MFMA GEMM v2: 128x128 tile, BK=64, 8 waves, 2-phase dbuf ------
template <int MODE>
__launch_bounds__(512, 4)
__global__ void k_gemm2(const short* __restrict__ A, const short* __restrict__ Bt,
                        short* __restrict__ out0, short* __restrict__ out1,
                        float* __restrict__ outF) {
    __shared__ short As[2][128][64];
    __shared__ short Bs[2][128][64];
    int t = threadIdx.x;
    int l = t & 63, w = t >> 6;
    int wm = w >> 2, wn = w & 3;
    int lr = l & 15, lg = l >> 4;
    int m0 = blockIdx.x * 128, n0 = blockIdx.y * 128;
    const short* Bp = Bt + (MODE == 0 ? ((size_t)blockIdx.z << 20) : 0);

    int srow = l >> 3;
    int sg = (l & 7) ^ srow;
    const short* Ab0 = A + (size_t)(m0 + w * 8 + srow) * 1024 + sg * 8;
    const short* Ab1 = Ab0 + 64 * 1024;
    const short* Bb0 = Bp + (size_t)(n0 + w * 8 + srow) * 1024 + sg * 8;
    const short* Bb1 = Bb0 + 64 * 1024;

    float4v acc[4][2] = {};

#define STAGE(bb, k0)                                   \
    do {                                                \
        GLD_LDS16(Ab0 + (k0), &As[bb][w * 8][0]);       \
        GLD_LDS16(Ab1 + (k0), &As[bb][64 + w * 8][0]);  \
        GLD_LDS16(Bb0 + (k0), &Bs[bb][w * 8][0]);       \
        GLD_LDS16(Bb1 + (k0), &Bs[bb][64 + w * 8][0]);  \
    } while (0)

    STAGE(0, 0);
    __syncthreads();
    int cur = 0;

    for (int kt = 0; kt < 16; kt++) {
        if (kt + 1 < 16) STAGE(cur ^ 1, (kt + 1) * 64);
#pragma unroll
        for (int ks = 0; ks < 2; ks++) {
            short8v af[4], bfv[2];
            int hh = ks * 4 + lg;
            int sw = ((hh ^ (lr & 7)) * 8);
#pragma unroll
            for (int fm = 0; fm < 4; fm++)
                af[fm] = *(const short8v*)&As[cur][wm * 64 + fm * 16 + lr][sw];
#pragma unroll
            for (int fn = 0; fn < 2; fn++)
                bfv[fn] = *(const short8v*)&Bs[cur][wn * 32 + fn * 16 + lr][sw];
            __builtin_amdgcn_s_setprio(1);
#pragma unroll
            for (int fm = 0; fm < 4; fm++)
#pragma unroll
                for (int fn = 0; fn < 2; fn++)
                    acc[fm][fn] = (MODE == 1)
                        ? __builtin_amdgcn_mfma_f32_16x16x32_bf16(bfv[fn], af[fm], acc[fm][fn], 0, 0, 0)
                        : __builtin_amdgcn_mfma_f32_16x16x32_bf16(af[fm], bfv[fn], acc[fm][fn], 0, 0, 0);
            __builtin_amdgcn_s_setprio(0);
        }
        __syncthreads();
        cur ^= 1;
    }
#undef STAGE

    if (MODE == 0) {
        short* out = (blockIdx.z == 0) ? out0 : out1;
        float scale = (blockIdx.z == 0) ? 0.125f * 1.44269504088896f : 1.0f;
#pragma unroll
        for (int fm = 0; fm < 4; fm++)
#pragma unroll
            for (int fn = 0; fn < 2; fn++)
#pragma unroll
                for (int r = 0; r < 4; r++) {
                    int m = m0 + wm * 64 + fm * 16 + lg * 4 + r;
                    int n = n0 + wn * 32 + fn * 16 + lr;
                    float v = acc[fm][fn][r] * scale;
                    int b = m >> 11, s = m & 2047, h = n >> 6, dh = n & 63;
                    out[(((size_t)(b * 16 + h)) * 2048 + s) * 64 + dh] = f2bf(v);
                }
    } else if (MODE == 1) {
#pragma unroll
        for (int fm = 0; fm < 4; fm++)
#pragma unroll
            for (int fn = 0; fn < 2; fn++)
#pragma unroll
                for (int r = 0; r < 4; r++) {
                    int n = n0 + wn * 32 + fn * 16 + lg * 4 + r;
                    int m = m0 + wm * 64 + fm * 16 + lr;
                    int b = m >> 11, s = m & 2047, h = n >> 6, dh = n & 63;
                    out0[(((size_t)(b * 16 + h)) * 64 + dh) * 2048 + s] = f2bf(acc[fm][fn][r]);
                }
    } else {
#pragma unroll
        for (int fm = 0; fm < 4; fm++)
#pragma unroll
            for (int fn = 0; fn < 2; fn++)
#pragma unroll
                for (int r = 0; r < 4; r++) {
                    int m = m0 + wm * 64 + fm * 16 + lg * 4 + r;
                    int n = n0 + wn * 32 + fn * 16 + lr;
                    outF[(size_t)m * 1024 + n] = acc[fm][fn][r];
                }
    }
}

// ---------------- causal flash attention v6 ----------------
// grid (32 bh, 32 tiles descending). Block = 2 waves x 32 q-rows = 64-row tile.
// K in LDS (dbuf, swizzled, async DMA); V^T direct via pinned asm global loads
// (unsinkable), counted vmcnt; 2 sub-tiles share K-frag reads and V-frags.
__launch_bounds__(128, 2)
__global__ void k_attn(const short* __restrict__ Qb, const short* __restrict__ Kb,
                       const short* __restrict__ Vtb, short* __restrict__ Ob) {
    __shared__ short K_lds[2][64][64];
    __shared__ short p_lds[2][16][72];
    int t = threadIdx.x;
    int l = t & 63, w = t >> 6;
    int lr = l & 15, lg = l >> 4;
    int bh = blockIdx.x;                 // bh%8 -> XCD; co-resident blocks share bh
    int tile = 31 - (int)blockIdx.y;     // longest tiles dispatched first (LPT)
    int nch = tile + 1;

    const short* Qp = Qb + (size_t)bh * 2048 * 64;
    const short* Kp = Kb + (size_t)bh * 2048 * 64;
    const short* Vp = Vtb + (size_t)bh * 64 * 2048;

    // K staging: 4 x 16B slots per thread, source-swizzled, linear LDS dest
    auto stageK = [&](int bb, int kv0) {
#pragma unroll
        for (int i = 0; i < 4; i++) {
            int s = t + i * 128;
            int row = s >> 3, cg = s & 7;
            int cs = (cg ^ (row & 7)) * 8;
            GLD_LDS16(&Kp[(size_t)(kv0 + row) * 64 + cs], (short*)K_lds[bb] + (size_t)s * 8);
        }
    };

    stageK(0, 0);

    int q0a = tile * 64 + w * 32;
    int q0b = q0a + 16;
    short8v qf0a = *(const short8v*)&Qp[(size_t)(q0a + lr) * 64 + lg * 8];
    short8v qf1a = *(const short8v*)&Qp[(size_t)(q0a + lr) * 64 + 32 + lg * 8];
    short8v qf0b = *(const short8v*)&Qp[(size_t)(q0b + lr) * 64 + lg * 8];
    short8v qf1b = *(const short8v*)&Qp[(size_t)(q0b + lr) * 64 + 32 + lg * 8];

    // per-lane V byte offsets (constant across chunks)
    int voff[4];
#pragma unroll
    for (int dt = 0; dt < 4; dt++) voff[dt] = (dt * 16 + lr) * 4096 + lg * 16;

    float4v oa[4] = {}, ob[4] = {};
    float mra[4] = {-3e38f, -3e38f, -3e38f, -3e38f};
    float mrb[4] = {-3e38f, -3e38f, -3e38f, -3e38f};
    float lsa[4] = {0.f, 0.f, 0.f, 0.f};
    float lsb[4] = {0.f, 0.f, 0.f, 0.f};
    int cur = 0;

    __syncthreads();   // prologue stage drained

    for (int ci = 0; ci < nch; ci++) {
        int kv0 = ci * 64;
        bool last = (ci == nch - 1);

        // ---- V fragment loads: pinned asm, issued first (8 vmcnt events) ----
        int4v vf[8];
        const short* vbase = Vp + kv0;
#pragma unroll
        for (int dt = 0; dt < 4; dt++) {
            asm volatile("global_load_dwordx4 %0, %1, %2 offset:0"
                         : "=v"(vf[dt]) : "v"(voff[dt]), "s"(vbase) : "memory");
            asm volatile("global_load_dwordx4 %0, %1, %2 offset:64"
                         : "=v"(vf[4 + dt]) : "v"(voff[dt]), "s"(vbase) : "memory");
        }

        // ---- stage next K chunk (4 vmcnt events) ----
        if (!last) stageK(cur ^ 1, kv0 + 64);

        // ---- QK^T for both sub-tiles from shared K-frags ----
        const short* Kf = (const short*)K_lds[cur];
        float4v sa[4] = {}, sb[4] = {};
        __builtin_amdgcn_s_setprio(1);
#pragma unroll
        for (int t4 = 0; t4 < 4; t4++) {
            int krow = t4 * 16 + lr;
            int sw = (krow & 7);
            short8v kfa = *(const short8v*)&Kf[krow * 64 + ((lg ^ sw) * 8)];
            short8v kfb = *(const short8v*)&Kf[krow * 64 + (((lg ^ 4) ^ sw) * 8)];
            sa[t4] = __builtin_amdgcn_mfma_f32_16x16x32_bf16(qf0a, kfa, sa[t4], 0, 0, 0);
            sa[t4] = __builtin_amdgcn_mfma_f32_16x16x32_bf16(qf1a, kfb, sa[t4], 0, 0, 0);
            sb[t4] = __builtin_amdgcn_mfma_f32_16x16x32_bf16(qf0b, kfa, sb[t4], 0, 0, 0);
            sb[t4] = __builtin_amdgcn_mfma_f32_16x16x32_bf16(qf1b, kfb, sb[t4], 0, 0, 0);
        }
        __builtin_amdgcn_s_setprio(0);

        if (last) {   // causal mask, boundary chunk only
#pragma unroll
            for (int t4 = 0; t4 < 4; t4++)
#pragma unroll
                for (int r = 0; r < 4; r++) {
                    int kvi = kv0 + t4 * 16 + lr;
                    if (kvi > q0a + lg * 4 + r) sa[t4][r] = -3e38f;
                    if (kvi > q0b + lg * 4 + r) sb[t4][r] = -3e38f;
                }
        }

        // ---- softmax A (defer-max, per-lane check) + P write A ----
        {
            float mx[4];
#pragma unroll
            for (int r = 0; r < 4; r++)
                mx[r] = fmaxf(fmaxf(sa[0][r], sa[1][r]), fmaxf(sa[2][r], sa[3][r]));
            float worst = fmaxf(fmaxf(mx[0] - mra[0], mx[1] - mra[1]),
                                fmaxf(mx[2] - mra[2], mx[3] - mra[3]));
            if (!__all(worst <= 8.f)) {
#pragma unroll
                for (int r = 0; r < 4; r++) {
                    float m_ = mx[r];
                    m_ = fmaxf(m_, __shfl_xor(m_, 1));
                    m_ = fmaxf(m_, __shfl_xor(m_, 2));
                    m_ = fmaxf(m_, __shfl_xor(m_, 4));
                    m_ = fmaxf(m_, __shfl_xor(m_, 8));
                    float mnew = fmaxf(mra[r], m_);
                    float sc = __builtin_amdgcn_exp2f(mra[r] - mnew);
                    mra[r] = mnew;
                    lsa[r] *= sc;
                    oa[0][r] *= sc; oa[1][r] *= sc; oa[2][r] *= sc; oa[3][r] *= sc;
                }
            }
#pragma unroll
            for (int r = 0; r < 4; r++) {
                float e0 = __builtin_amdgcn_exp2f(sa[0][r] - mra[r]);
                float e1 = __builtin_amdgcn_exp2f(sa[1][r] - mra[r]);
                float e2 = __builtin_amdgcn_exp2f(sa[2][r] - mra[r]);
                float e3 = __builtin_amdgcn_exp2f(sa[3][r] - mra[r]);
                lsa[r] += (e0 + e1) + (e2 + e3);
                p_lds[w][lg * 4 + r][lr]      = f2bf(e0);
                p_lds[w][lg * 4 + r][16 + lr] = f2bf(e1);
                p_lds[w][lg * 4 + r][32 + lr] = f2bf(e2);
                p_lds[w][lg * 4 + r][48 + lr] = f2bf(e3);
            }
        }
        short8v pa0 = *(const short8v*)&p_lds[w][lr][lg * 8];
        short8v pa1 = *(const short8v*)&p_lds[w][lr][32 + lg * 8];

        // ---- V ready? counted wait: keep next-chunk staging in flight ----
        if (last) asm volatile("s_waitcnt vmcnt(0)" ::: "memory");
        else      asm volatile("s_waitcnt vmcnt(4)" ::: "memory");
        __builtin_amdgcn_sched_barrier(0);

        // ---- PV A ----
        __builtin_amdgcn_s_setprio(1);
#pragma unroll
        for (int dt = 0; dt < 4; dt++) {
            oa[dt] = __builtin_amdgcn_mfma_f32_16x16x32_bf16(pa0, __builtin_bit_cast(short8v, vf[dt]), oa[dt], 0, 0, 0);
            oa[dt] = __builtin_amdgcn_mfma_f32_16x16x32_bf16(pa1, __builtin_bit_cast(short8v, vf[4 + dt]), oa[dt], 0, 0, 0);
        }
        __builtin_amdgcn_s_setprio(0);

        // ---- softmax B + P write B + PV B (reuses vf) ----
        {
            float mx[4];
#pragma unroll
            for (int r = 0; r < 4; r++)
                mx[r] = fmaxf(fmaxf(sb[0][r], sb[1][r]), fmaxf(sb[2][r], sb[3][r]));
            float worst = fmaxf(fmaxf(mx[0] - mrb[0], mx[1] - mrb[1]),
                                fmaxf(mx[2] - mrb[2], mx[3] - mrb[3]));
            if (!__all(worst <= 8.f)) {
#pragma unroll
                for (int r = 0; r < 4; r++) {
                    float m_ = mx[r];
                    m_ = fmaxf(m_, __shfl_xor(m_, 1));
                    m_ = fmaxf(m_, __shfl_xor(m_, 2));
                    m_ = fmaxf(m_, __shfl_xor(m_, 4));
                    m_ = fmaxf(m_, __shfl_xor(m_, 8));
                    float mnew = fmaxf(mrb[r], m_);
                    float sc = __builtin_amdgcn_exp2f(mrb[r] - mnew);
                    mrb[r] = mnew;
                    lsb[r] *= sc;
                    ob[0][r] *= sc; ob[1][r] *= sc; ob[2][r] *= sc; ob[3][r] *= sc;
                }
            }
#pragma unroll
            for (int r = 0; r < 4; r++) {
                float e0 = __builtin_amdgcn_exp2f(sb[0][r] - mrb[r]);
                float e1 = __builtin_amdgcn_exp2f(sb[1][r] - mrb[r]);
                float e2 = __builtin_amdgcn_exp2f(sb[2][r] - mrb[r]);
                float e3 = __builtin_amdgcn_exp2f(sb[3][r] - mrb[r]);
                lsb[r] += (e0 + e1) + (e2 + e3);
                p_lds[w][lg * 4 + r][lr]      = f2bf(e0);
                p_lds[w][lg * 4 + r][16 + lr] = f2bf(e1);
                p_lds[w][lg * 4 + r][32 + lr] = f2bf(e2);
                p_lds[w][lg * 4 + r][48 + lr] = f2bf(e3);
            }
        }
        short8v pb0 = *(const short8v*)&p_lds[w][lr][lg * 8];
        short8v pb1 = *(const short8v*)&p_lds[w][lr][32 + lg * 8];

        __builtin_amdgcn_s_setprio(1);
#pragma unroll
        for (int dt = 0; dt < 4; dt++) {
            ob[dt] = __builtin_amdgcn_mfma_f32_16x16x32_bf16(pb0, __builtin_bit_cast(short8v, vf[dt]), ob[dt], 0, 0, 0);
            ob[dt] = __builtin_amdgcn_mfma_f32_16x16x32_bf16(pb1, __builtin_bit_cast(short8v, vf[4 + dt]), ob[dt], 0, 0, 0);
        }
        __builtin_amdgcn_s_setprio(0);

        __syncthreads();   // K buffer flip (drains staging + all LDS reads)
        cur ^= 1;
    }

    // ---- finalize both sub-tiles ----
    int b = bh >> 4, h = bh & 15;
#pragma unroll
    for (int r = 0; r < 4; r++) {
        float la = lsa[r], lb = lsb[r];
        la += __shfl_xor(la, 1); la += __shfl_xor(la, 2);
        la += __shfl_xor(la, 4); la += __shfl_xor(la, 8);
        lb += __shfl_xor(lb, 1); lb += __shfl_xor(lb, 2);
        lb += __shfl_xor(lb, 4); lb += __shfl_xor(lb, 8);
        lsa[r] = 1.0f / la;
        lsb[r] = 1.0f / lb;
    }
#pragma unroll
    for (int dt = 0; dt < 4; dt++)
#pragma unroll
        for (int r = 0; r < 4; r++) {
            int qa = q0a + lg * 4 + r;
            int qb2 = q0b + lg * 4 + r;
            Ob[((size_t)(b * 2048 + qa)) * 1024 + h * 64 + dt * 16 + lr] = f2bf(oa[dt][r] * lsa[r]);
            Ob[((size_t)(b * 2048 + qb2)) * 1024 + h * 64 + dt * 16 + lr] = f2bf(ob[dt][r] * lsb[r]);
        }
}

extern "C" void kernel_launch(void* const* d_in, const int* in_sizes, int n_in,
                              void* d_out, int out_size, void* d_ws, size_t ws_size,
                              hipStream_t stream) {
    const float* x  = (const float*)d_in[0];
    const float* Wq = (const float*)d_in[1];
    const float* Wk = (const float*)d_in[2];
    const float* Wv = (const float*)d_in[3];
    const float* Wo = (const float*)d_in[4];
    float* out = (float*)d_out;

    char* ws = (char*)d_ws;
    short* xb  = (short*)(ws);                 // [4096][1024] bf16       8 MB
    short* Wtb = (short*)(ws + 8388608);       // 4 x [1024 n][1024 k]    8 MB
    short* Qb  = (short*)(ws + 16777216);      // [B,H,S,Dh] (pre-scaled) 8 MB
    short* Kb  = (short*)(ws + 25165824);      // [B,H,S,Dh]              8 MB
    short* Vtb = (short*)(ws + 33554432);      // [B,H,Dh,S]              8 MB
    short* Ob  = (short*)(ws + 41943040);      // [B,S,D] bf16            8 MB

    k_cvt_x<<<4096, 256, 0, stream>>>(x, xb);
    k_transpose<<<dim3(32, 32, 4), dim3(32, 8), 0, stream>>>(Wq, Wk, Wv, Wo, Wtb);
    k_gemm2<0><<<dim3(32, 8, 2), 512, 0, stream>>>(xb, Wtb, Qb, Kb, nullptr);
    k_gemm2<1><<<dim3(32, 8), 512, 0, stream>>>(xb, Wtb + 2 * 1048576, Vtb, nullptr, nullptr);
    k_attn<<<dim3(32, 32), 128, 0, stream>>>(Qb, Kb, Vtb, Ob);
    k_gemm2<2><<<dim3(32, 8), 512, 0, stream>>>(Ob, Wtb + 3 * 1048576, nullptr, nullptr, out);
}